// Round 17
// baseline (457.110 us; speedup 1.0000x reference)
//
#include <hip/hip_runtime.h>
#include <hip/hip_bf16.h>
#include <math.h>

namespace {

constexpr int Bc  = 32;
constexpr int Tc  = 1024;
constexpr int Dc  = 1024;
constexpr int Nt  = 77;
constexpr int Lc  = 768;
constexpr int HDc = 128;
constexpr int TEDc = 2048;
constexpr float EPSc = 1e-5f;

typedef __attribute__((ext_vector_type(8))) short bf16x8;
typedef __attribute__((ext_vector_type(8))) unsigned short u16x8;
typedef __attribute__((ext_vector_type(4))) float f32x4;

__device__ __forceinline__ float silu_f(float x) { return x / (1.f + __expf(-x)); }

__device__ __forceinline__ unsigned short f2bf(float f) {
  unsigned u = __float_as_uint(f);
  return (unsigned short)((u + 0x7fffu + ((u >> 16) & 1u)) >> 16);
}
__device__ __forceinline__ float bf2f(unsigned short h) {
  return __uint_as_float(((unsigned)h) << 16);
}

__device__ __forceinline__ void gload16(const void* g, void* l) {
  __builtin_amdgcn_global_load_lds((const __attribute__((address_space(1))) void*)g,
                                   (__attribute__((address_space(3))) void*)l, 16, 0, 0);
}

// swizzle term for a 16-row x 64B LDS chunk (r8-verified: conflicts 8.39M -> 0)
__device__ __forceinline__ int rowswz(int r) {
  return (((r >> 3) & 1) << 1) | ((r >> 1) & 1);
}

// ---------- LayerNorm -> bf16, wave-per-row (no barriers; COLS template => regs) --------
template<int COLS>
__global__ __launch_bounds__(256) void ln_bf16_wave_kernel(
    const float* __restrict__ src, unsigned short* __restrict__ dst,
    const float* __restrict__ g, const float* __restrict__ b, int rows)
{
  constexpr int NJ = COLS / 256;
  const int row = blockIdx.x * 4 + (threadIdx.x >> 6);
  if (row >= rows) return;
  const int lane = threadIdx.x & 63;
  const float* p = src + (size_t)row * COLS;
  float4 v[NJ];
  float s = 0.f, sq = 0.f;
  #pragma unroll
  for (int j = 0; j < NJ; j++) {
    v[j] = *reinterpret_cast<const float4*>(p + (j * 64 + lane) * 4);
    s  += v[j].x + v[j].y + v[j].z + v[j].w;
    sq += v[j].x * v[j].x + v[j].y * v[j].y + v[j].z * v[j].z + v[j].w * v[j].w;
  }
  #pragma unroll
  for (int o = 32; o > 0; o >>= 1) { s += __shfl_xor(s, o); sq += __shfl_xor(sq, o); }
  const float mean = s / COLS;
  const float rstd = rsqrtf(sq / COLS - mean * mean + EPSc);
  #pragma unroll
  for (int j = 0; j < NJ; j++) {
    const int c = (j * 64 + lane) * 4;
    ushort4 o4;
    o4.x = f2bf((v[j].x - mean) * rstd * g[c + 0] + b[c + 0]);
    o4.y = f2bf((v[j].y - mean) * rstd * g[c + 1] + b[c + 1]);
    o4.z = f2bf((v[j].z - mean) * rstd * g[c + 2] + b[c + 2]);
    o4.w = f2bf((v[j].w - mean) * rstd * g[c + 3] + b[c + 3]);
    *reinterpret_cast<ushort4*>(dst + (size_t)row * COLS + c) = o4;
  }
}

// ---------- transpose-convert W[K][N] f32 -> Wt[N][K] bf16 ------------------------------
__global__ __launch_bounds__(256) void convT_bf16_kernel(
    const float* __restrict__ W, unsigned short* __restrict__ Wt, int K, int N)
{
  __shared__ float t[32][33];
  const int n0 = blockIdx.x * 32, k0 = blockIdx.y * 32;
  const int tx = threadIdx.x & 31, ty = threadIdx.x >> 5;
  #pragma unroll
  for (int dy = 0; dy < 32; dy += 8)
    t[ty + dy][tx] = W[(size_t)(k0 + ty + dy) * N + n0 + tx];
  __syncthreads();
  #pragma unroll
  for (int dy = 0; dy < 32; dy += 8)
    Wt[(size_t)(n0 + ty + dy) * K + k0 + tx] = f2bf(t[tx][ty + dy]);
}

// same, two matrices selected by blockIdx.z (Wk / Wv share shape)
__global__ __launch_bounds__(256) void convT2_bf16_kernel(
    const float* __restrict__ W0, unsigned short* __restrict__ T0,
    const float* __restrict__ W1, unsigned short* __restrict__ T1, int K, int N)
{
  __shared__ float t[32][33];
  const float* W = blockIdx.z ? W1 : W0;
  unsigned short* Wt = blockIdx.z ? T1 : T0;
  const int n0 = blockIdx.x * 32, k0 = blockIdx.y * 32;
  const int tx = threadIdx.x & 31, ty = threadIdx.x >> 5;
  #pragma unroll
  for (int dy = 0; dy < 32; dy += 8)
    t[ty + dy][tx] = W[(size_t)(k0 + ty + dy) * N + n0 + tx];
  __syncthreads();
  #pragma unroll
  for (int dy = 0; dy < 32; dy += 8)
    Wt[(size_t)(n0 + ty + dy) * K + k0 + tx] = f2bf(t[tx][ty + dy]);
}

// ---------- bf16 MFMA GEMM, 256x128 tile, 8 waves, 3-deep pipeline, counted vmcnt -------
// (r12 core — best-measured passing GEMM across 13 structural variants this session)
template<int EPI, int NT>
__global__ __launch_bounds__(512, 4) void gemm2_kernel(
    const unsigned short* __restrict__ A, const unsigned short* __restrict__ Bt,
    const float* __restrict__ bias, const float* __restrict__ bias2, int bsplit,
    void* __restrict__ Cout, int M, int N, const float* __restrict__ xres)
{
  constexpr int K = NT * 32;
  __shared__ unsigned short lds[36864];   // 72 KB (EPI2 reuses [0,32768) for C-tile)
  const int tid = threadIdx.x, wid = tid >> 6, lane = tid & 63;
  const int ntx = N >> 7;
  int swz = blockIdx.x;
  const int nwg = gridDim.x;
  if ((nwg & 7) == 0) { const int cpx = nwg >> 3; swz = (swz & 7) * cpx + (swz >> 3); }
  const int bx = swz % ntx, by = swz / ntx;
  const int bm0 = by << 8, bn0 = bx << 7;
  const int wr = wid >> 1, wc = wid & 1, lhi = lane >> 4, llo = lane & 15;

  const int srow = lane >> 2;
  const int scol = (((lane & 3) ^ rowswz(srow)) * 8);
  int ar0 = bm0 + wid * 32 + srow;      if (ar0 >= M) ar0 = M - 1;
  int ar1 = bm0 + wid * 32 + 16 + srow; if (ar1 >= M) ar1 = M - 1;
  const int br = bn0 + wid * 16 + srow;
  const unsigned short* Ag0 = A  + (size_t)ar0 * K + scol;
  const unsigned short* Ag1 = A  + (size_t)ar1 * K + scol;
  const unsigned short* Bg  = Bt + (size_t)br  * K + scol;
  const int alc0 = (wid * 2) * 512, alc1 = (wid * 2 + 1) * 512, blc = wid * 512;
  const int rx = rowswz(llo);
  const int aoff = wr * 2048 + llo * 32 + ((lhi ^ rx) * 8);
  const int boff = wc * 2048 + llo * 32 + ((lhi ^ rx) * 8);

  f32x4 acc[4][4] = {};

  gload16(Ag0,      &lds[alc0]);
  gload16(Ag1,      &lds[alc1]);
  gload16(Bg,       &lds[24576 + blc]);
  gload16(Ag0 + 32, &lds[8192 + alc0]);
  gload16(Ag1 + 32, &lds[8192 + alc1]);
  gload16(Bg  + 32, &lds[24576 + 4096 + blc]);

  for (int t = 0; t < NT; t += 3) {
    #pragma unroll
    for (int j = 0; j < 3; j++) {
      const int tt = t + j;
      if (tt < NT) {
        if (tt + 2 < NT) {
          const int k2 = (tt + 2) << 5;
          constexpr int PB0 = 2, PB1 = 0, PB2 = 1;
          const int pb = (j == 0) ? PB0 : (j == 1) ? PB1 : PB2;
          gload16(Ag0 + k2, &lds[pb * 8192 + alc0]);
          gload16(Ag1 + k2, &lds[pb * 8192 + alc1]);
          gload16(Bg  + k2, &lds[24576 + pb * 4096 + blc]);
          asm volatile("s_waitcnt vmcnt(6)" ::: "memory");
        } else if (tt + 1 < NT) {
          asm volatile("s_waitcnt vmcnt(3)" ::: "memory");
        } else {
          asm volatile("s_waitcnt vmcnt(0)" ::: "memory");
        }
        __builtin_amdgcn_s_barrier();
        bf16x8 a_[4], b_[4];
        #pragma unroll
        for (int mi = 0; mi < 4; mi++)
          a_[mi] = *(const bf16x8*)(&lds[j * 8192 + aoff + mi * 512]);
        #pragma unroll
        for (int ni = 0; ni < 4; ni++)
          b_[ni] = *(const bf16x8*)(&lds[24576 + j * 4096 + boff + ni * 512]);
        __builtin_amdgcn_s_setprio(1);
        #pragma unroll
        for (int mi = 0; mi < 4; mi++)
          #pragma unroll
          for (int ni = 0; ni < 4; ni++)
            acc[mi][ni] = __builtin_amdgcn_mfma_f32_16x16x32_bf16(a_[mi], b_[ni], acc[mi][ni], 0, 0, 0);
        __builtin_amdgcn_s_setprio(0);
        __builtin_amdgcn_s_barrier();
      }
    }
  }

  if constexpr (EPI != 2) {
    #pragma unroll
    for (int mi = 0; mi < 4; mi++) {
      #pragma unroll
      for (int ni = 0; ni < 4; ni++) {
        const int col = bn0 + wc * 64 + ni * 16 + llo;
        const float bs = (bsplit > 0 && col >= bsplit) ? bias2[col - bsplit] : bias[col];
        #pragma unroll
        for (int r = 0; r < 4; r++) {
          const int row = bm0 + wr * 64 + mi * 16 + lhi * 4 + r;
          if (row < M) {
            float v = acc[mi][ni][r] + bs;
            if (EPI == 1) v += xres[(size_t)row * N + col];
            ((float*)Cout)[(size_t)row * N + col] = v;
          }
        }
      }
    }
  } else {
    // ---- fused head-dim softmax epilogue (tile N-width == head_dim == 128) ----
    __syncthreads();
    #pragma unroll
    for (int mi = 0; mi < 4; mi++) {
      #pragma unroll
      for (int ni = 0; ni < 4; ni++) {
        const int col = wc * 64 + ni * 16 + llo;
        const float bs = bias[bn0 + col];
        #pragma unroll
        for (int r = 0; r < 4; r++) {
          const int row = wr * 64 + mi * 16 + lhi * 4 + r;
          lds[row * 128 + (col ^ ((row & 7) << 3))] = f2bf(acc[mi][ni][r] + bs);
        }
      }
    }
    __syncthreads();
    const int row = tid >> 1, cb = (tid & 1) * 64;
    const int sw = (row & 7) << 3;
    float mx = -1e30f;
    #pragma unroll
    for (int g = 0; g < 8; g++) {
      u16x8 u = *(const u16x8*)(&lds[row * 128 + ((cb + g * 8) ^ sw)]);
      #pragma unroll
      for (int j = 0; j < 8; j++) mx = fmaxf(mx, bf2f(u[j]));
    }
    mx = fmaxf(mx, __shfl_xor(mx, 1));
    float ssum = 0.f;
    #pragma unroll
    for (int g = 0; g < 8; g++) {
      unsigned short* p = &lds[row * 128 + ((cb + g * 8) ^ sw)];
      u16x8 u = *(const u16x8*)p;
      u16x8 e;
      #pragma unroll
      for (int j = 0; j < 8; j++) {
        float ev = __expf(bf2f(u[j]) - mx);
        ssum += ev;
        e[j] = f2bf(ev);
      }
      *(u16x8*)p = e;
    }
    ssum += __shfl_xor(ssum, 1);
    const float inv = 1.f / ssum;
    unsigned short* Cb = (unsigned short*)Cout;
    #pragma unroll
    for (int g = 0; g < 8; g++) {
      u16x8 u = *(const u16x8*)(&lds[row * 128 + ((cb + g * 8) ^ sw)]);
      u16x8 o;
      #pragma unroll
      for (int j = 0; j < 8; j++) o[j] = f2bf(bf2f(u[j]) * inv);
      *(u16x8*)(&Cb[(size_t)(bm0 + row) * N + bn0 + cb + g * 8]) = o;
    }
  }
}

// ---------- attn: fused column-softmax(k over N) + attnT einsum (bf16 out) --------------
__global__ __launch_bounds__(256) void attn_fused_kernel(
    const float* __restrict__ kv, unsigned short* __restrict__ attnT) {
  const int bh = blockIdx.x;
  const int b = bh >> 3, h = bh & 7;
  __shared__ float ks[Nt][HDc];
  __shared__ float vs[Nt][HDc];
  const float* kb = kv + (size_t)b * Nt * 2048 + h * HDc;
  const float* vb = kv + (size_t)b * Nt * 2048 + 1024 + h * HDc;
  for (int i = threadIdx.x; i < Nt * HDc; i += 256) {
    const int n = i >> 7, d = i & 127;
    ks[n][d] = kb[(size_t)n * 2048 + d];
    vs[n][d] = vb[(size_t)n * 2048 + d];
  }
  __syncthreads();
  if (threadIdx.x < HDc) {
    const int d = threadIdx.x;
    float m = -1e30f;
    for (int n = 0; n < Nt; n++) m = fmaxf(m, ks[n][d]);
    float s = 0.f;
    for (int n = 0; n < Nt; n++) { float e = __expf(ks[n][d] - m); ks[n][d] = e; s += e; }
    const float inv = 1.f / s;
    for (int n = 0; n < Nt; n++) ks[n][d] *= inv;
  }
  __syncthreads();
  const int tx = threadIdx.x & 15, ty = threadIdx.x >> 4;
  float acc[8][8] = {};
  for (int n = 0; n < Nt; n++) {
    float a[8], w[8];
    #pragma unroll
    for (int i = 0; i < 8; i++) a[i] = vs[n][ty + 16 * i];
    #pragma unroll
    for (int j = 0; j < 8; j++) w[j] = ks[n][tx + 16 * j];
    #pragma unroll
    for (int i = 0; i < 8; i++)
      #pragma unroll
      for (int j = 0; j < 8; j++)
        acc[i][j] += a[i] * w[j];
  }
  unsigned short* ab = attnT + (size_t)bh * HDc * HDc;
  #pragma unroll
  for (int i = 0; i < 8; i++)
    #pragma unroll
    for (int j = 0; j < 8; j++)
      ab[(size_t)(ty + 16 * i) * HDc + tx + 16 * j] = f2bf(acc[i][j]);
}

// ---------- y = q @ attn per (b,h), MFMA 2-phase, coalesced epilogue, in place ----------
__global__ __launch_bounds__(256) void y_mfma_kernel(
    unsigned short* __restrict__ q, const unsigned short* __restrict__ attnT)
{
  __shared__ unsigned short lds[16384];
  const int tid = threadIdx.x, wid = tid >> 6, lane = tid & 63;
  const int bh = blockIdx.y, b = bh >> 3, h = bh & 7;
  const int bm0 = blockIdx.x << 7;
  const int wr = wid >> 1, wc = wid & 1, lhi = lane >> 4, llo = lane & 15;

  unsigned short* Abase = q + ((size_t)b * Tc) * Dc + h * HDc;
  const unsigned short* Btb = attnT + (size_t)bh * HDc * HDc;

  const int srow = lane >> 2, scol = (lane & 3) * 8;
  const int ar0 = bm0 + wid * 32 + srow, ar1 = ar0 + 16;
  const int br0 = wid * 32 + srow,       br1 = br0 + 16;
  const unsigned short* Ag0 = Abase + (size_t)ar0 * Dc + scol;
  const unsigned short* Ag1 = Abase + (size_t)ar1 * Dc + scol;
  const unsigned short* Bg0 = Btb + (size_t)br0 * HDc + scol;
  const unsigned short* Bg1 = Btb + (size_t)br1 * HDc + scol;
  const int lc0 = (wid * 2 + 0) * 512, lc1 = (wid * 2 + 1) * 512;
  const int aoff = wr * 2048 + llo * 32 + lhi * 8;
  const int boff = wc * 2048 + llo * 32 + lhi * 8;

  f32x4 acc[4][4] = {};

  gload16(Ag0, &lds[lc0]);
  gload16(Ag1, &lds[lc1]);
  gload16(Bg0, &lds[8192 + lc0]);
  gload16(Bg1, &lds[8192 + lc1]);
  __syncthreads();

  int cur = 0;
  for (int t = 1; t < 4; ++t) {
    const int nb = cur ^ 1;
    const int k0 = t << 5;
    gload16(Ag0 + k0, &lds[nb * 4096 + lc0]);
    gload16(Ag1 + k0, &lds[nb * 4096 + lc1]);
    gload16(Bg0 + k0, &lds[8192 + nb * 4096 + lc0]);
    gload16(Bg1 + k0, &lds[8192 + nb * 4096 + lc1]);
    bf16x8 a_[4], b_[4];
    #pragma unroll
    for (int mi = 0; mi < 4; mi++) a_[mi] = *(const bf16x8*)(&lds[cur * 4096 + aoff + mi * 512]);
    #pragma unroll
    for (int ni = 0; ni < 4; ni++) b_[ni] = *(const bf16x8*)(&lds[8192 + cur * 4096 + boff + ni * 512]);
    #pragma unroll
    for (int mi = 0; mi < 4; mi++)
      #pragma unroll
      for (int ni = 0; ni < 4; ni++)
        acc[mi][ni] = __builtin_amdgcn_mfma_f32_16x16x32_bf16(a_[mi], b_[ni], acc[mi][ni], 0, 0, 0);
    __syncthreads();
    cur = nb;
  }
  {
    bf16x8 a_[4], b_[4];
    #pragma unroll
    for (int mi = 0; mi < 4; mi++) a_[mi] = *(const bf16x8*)(&lds[cur * 4096 + aoff + mi * 512]);
    #pragma unroll
    for (int ni = 0; ni < 4; ni++) b_[ni] = *(const bf16x8*)(&lds[8192 + cur * 4096 + boff + ni * 512]);
    #pragma unroll
    for (int mi = 0; mi < 4; mi++)
      #pragma unroll
      for (int ni = 0; ni < 4; ni++)
        acc[mi][ni] = __builtin_amdgcn_mfma_f32_16x16x32_bf16(a_[mi], b_[ni], acc[mi][ni], 0, 0, 0);
  }

  __syncthreads();
  #pragma unroll
  for (int mi = 0; mi < 4; mi++) {
    #pragma unroll
    for (int ni = 0; ni < 4; ni++) {
      const int col = wc * 64 + ni * 16 + llo;
      #pragma unroll
      for (int r = 0; r < 4; r++) {
        const int row = wr * 64 + mi * 16 + lhi * 4 + r;
        lds[row * 128 + (col ^ ((row & 7) << 3))] = f2bf(acc[mi][ni][r]);
      }
    }
  }
  __syncthreads();
  const int row = tid >> 1, cb = (tid & 1) * 64;
  const int sw = (row & 7) << 3;
  #pragma unroll
  for (int g = 0; g < 8; g++) {
    u16x8 u = *(const u16x8*)(&lds[row * 128 + ((cb + g * 8) ^ sw)]);
    *(u16x8*)(&Abase[(size_t)(bm0 + row) * Dc + cb + g * 8]) = u;
  }
}

// ---------- LN(y)*(1+scale)+shift -> SiLU, wave-per-row, in place (bf16) ----------------
__global__ __launch_bounds__(256) void ln_mod_silu_wave_kernel(
    unsigned short* __restrict__ y, const float* __restrict__ ss,
    const float* __restrict__ g, const float* __restrict__ bvec) {
  const int row = blockIdx.x * 4 + (threadIdx.x >> 6);
  const int lane = threadIdx.x & 63;
  const int b = row >> 10;
  unsigned short* p = y + (size_t)row * Dc;
  float4 v[4];
  float s = 0.f, sq = 0.f;
  #pragma unroll
  for (int j = 0; j < 4; j++) {
    ushort4 u = *reinterpret_cast<const ushort4*>(p + (j * 64 + lane) * 4);
    v[j] = make_float4(bf2f(u.x), bf2f(u.y), bf2f(u.z), bf2f(u.w));
    s  += v[j].x + v[j].y + v[j].z + v[j].w;
    sq += v[j].x * v[j].x + v[j].y * v[j].y + v[j].z * v[j].z + v[j].w * v[j].w;
  }
  #pragma unroll
  for (int o = 32; o > 0; o >>= 1) { s += __shfl_xor(s, o); sq += __shfl_xor(sq, o); }
  const float mean = s / 1024.f;
  const float rstd = rsqrtf(sq / 1024.f - mean * mean + EPSc);
  const float* ssb = ss + (size_t)b * 2048;
  #pragma unroll
  for (int j = 0; j < 4; j++) {
    const int c = (j * 64 + lane) * 4;
    ushort4 o4;
    float t0 = (v[j].x - mean) * rstd * g[c + 0] + bvec[c + 0];
    float t1 = (v[j].y - mean) * rstd * g[c + 1] + bvec[c + 1];
    float t2 = (v[j].z - mean) * rstd * g[c + 2] + bvec[c + 2];
    float t3 = (v[j].w - mean) * rstd * g[c + 3] + bvec[c + 3];
    o4.x = f2bf(silu_f(t0 * (1.f + ssb[c + 0]) + ssb[1024 + c + 0]));
    o4.y = f2bf(silu_f(t1 * (1.f + ssb[c + 1]) + ssb[1024 + c + 1]));
    o4.z = f2bf(silu_f(t2 * (1.f + ssb[c + 2]) + ssb[1024 + c + 2]));
    o4.w = f2bf(silu_f(t3 * (1.f + ssb[c + 3]) + ssb[1024 + c + 3]));
    *reinterpret_cast<ushort4*>(p + c) = o4;
  }
}

// ---------- emb projection: silu precompute, split-K partial GEMM, reduce ---------------
__global__ __launch_bounds__(256) void silu_emb_kernel(
    const float* __restrict__ emb, float* __restrict__ sile) {
  const int i = (blockIdx.x * 256 + threadIdx.x) * 4;
  float4 v = *reinterpret_cast<const float4*>(emb + i);
  v.x = silu_f(v.x); v.y = silu_f(v.y); v.z = silu_f(v.z); v.w = silu_f(v.w);
  *reinterpret_cast<float4*>(sile + i) = v;
}

__global__ __launch_bounds__(256) void emb_part_kernel(
    const float* __restrict__ sile, const float* __restrict__ W,
    float* __restrict__ part) {
  const int split = blockIdx.y;
  const int n = blockIdx.x * 256 + threadIdx.x;
  const int k0 = split * 64;
  const float* se = sile + k0;
  const float* Wp = W + (size_t)k0 * (2 * Dc) + n;
  float acc[32] = {};
  for (int kk = 0; kk < 64; kk++) {
    const float w = Wp[(size_t)kk * (2 * Dc)];
    #pragma unroll
    for (int m = 0; m < 32; m++)
      acc[m] = fmaf(se[m * TEDc + kk], w, acc[m]);
  }
  float* pp = part + (size_t)split * 32 * (2 * Dc) + n;
  #pragma unroll
  for (int m = 0; m < 32; m++) pp[(size_t)m * (2 * Dc)] = acc[m];
}

__global__ __launch_bounds__(256) void emb_reduce_kernel(
    const float* __restrict__ part, const float* __restrict__ bias,
    float* __restrict__ ssb) {
  const int i = blockIdx.x * 256 + threadIdx.x;
  const int n = i & (2 * Dc - 1);
  float s = bias[n];
  #pragma unroll 8
  for (int sp = 0; sp < 32; sp++) s += part[(size_t)sp * 32 * (2 * Dc) + i];
  ssb[i] = s;
}

}  // namespace

extern "C" void kernel_launch(void* const* d_in, const int* in_sizes, int n_in,
                              void* d_out, int out_size, void* d_ws, size_t ws_size,
                              hipStream_t stream) {
  const float* x       = (const float*)d_in[0];
  const float* xf      = (const float*)d_in[1];
  const float* emb     = (const float*)d_in[2];
  const float* norm_g  = (const float*)d_in[3];
  const float* norm_b  = (const float*)d_in[4];
  const float* tnorm_g = (const float*)d_in[5];
  const float* tnorm_b = (const float*)d_in[6];
  const float* Wq      = (const float*)d_in[7];
  const float* bq      = (const float*)d_in[8];
  const float* Wk      = (const float*)d_in[9];
  const float* bk      = (const float*)d_in[10];
  const float* Wv      = (const float*)d_in[11];
  const float* bv_     = (const float*)d_in[12];
  const float* emb_W   = (const float*)d_in[13];
  const float* emb_b   = (const float*)d_in[14];
  const float* onorm_g = (const float*)d_in[15];
  const float* onorm_b = (const float*)d_in[16];
  const float* Wo      = (const float*)d_in[17];
  const float* bo      = (const float*)d_in[18];
  float* out = (float*)d_out;

  char* ws = (char*)d_ws;
  unsigned short* Ab = (unsigned short*)ws;                       // [32768][1024] bf16
  char* R = ws;                                                   // aliased after q-GEMM
  unsigned short* qb   = (unsigned short*)(ws + 67108864);        // [32768][1024] bf16
  unsigned short* Wq_t = (unsigned short*)(ws + 134217728);
  unsigned short* Wk_t = (unsigned short*)(ws + 136314880);       // [Wk_t|Wv_t] contiguous
  unsigned short* Wv_t = (unsigned short*)(ws + 137887744);
  unsigned short* Wo_t = (unsigned short*)(ws + 139460608);
  float*          ssb  = (float*)(ws + 141557760);                // [32][2048]
  float*          sile = (float*)(ws + 141819904);                // [32][2048]
  float*          part = (float*)(ws + 142082048);                // [32][32][2048]
  // kv-phase aliases inside R (stream-serial after q-GEMM consumed Ab):
  unsigned short* xfb   = (unsigned short*)(R);                   // [2464][768] bf16
  float*          kv    = (float*)(R + 3784704);                  // [2464][2048] f32
  unsigned short* attnT = (unsigned short*)(R + 23969792);        // [256][128][128] bf16

  const int Mq  = Bc * Tc;   // 32768
  const int Mkv = Bc * Nt;   // 2464

  // ---- q path ----
  ln_bf16_wave_kernel<1024><<<Mq / 4, 256, 0, stream>>>(x, Ab, norm_g, norm_b, Mq);
  convT_bf16_kernel<<<dim3(Dc / 32, Dc / 32), 256, 0, stream>>>(Wq, Wq_t, Dc, Dc);
  convT2_bf16_kernel<<<dim3(Dc / 32, Lc / 32, 2), 256, 0, stream>>>(Wk, Wk_t, Wv, Wv_t, Lc, Dc);
  convT_bf16_kernel<<<dim3(Dc / 32, Dc / 32), 256, 0, stream>>>(Wo, Wo_t, Dc, Dc);

  // q = softmax_head(LN(x) @ Wq + bq), fused epilogue   (K=1024 -> NT=32)
  gemm2_kernel<2, 32><<<(Dc / 128) * (Mq / 256), 512, 0, stream>>>(
      Ab, Wq_t, bq, nullptr, 0, qb, Mq, Dc, nullptr);

  // ---- kv path (merged k+v GEMM; Wk_t|Wv_t contiguous as [2048][768]; K=768 -> NT=24) --
  ln_bf16_wave_kernel<768><<<Mkv / 4, 256, 0, stream>>>(xf, xfb, tnorm_g, tnorm_b, Mkv);
  gemm2_kernel<0, 24><<<(2048 / 128) * ((Mkv + 255) / 256), 512, 0, stream>>>(
      xfb, Wk_t, bk, bv_, 1024, kv, Mkv, 2048, nullptr);
  attn_fused_kernel<<<Bc * 8, 256, 0, stream>>>(kv, attnT);

  // ---- FiLM params: split-K ----
  silu_emb_kernel<<<(Bc * TEDc) / 1024, 256, 0, stream>>>(emb, sile);
  emb_part_kernel<<<dim3(8, 32), 256, 0, stream>>>(sile, emb_W, part);
  emb_reduce_kernel<<<(Bc * 2 * Dc) / 256, 256, 0, stream>>>(part, emb_b, ssb);

  // ---- y = q @ attn (MFMA, in place), LN+mod+SiLU (wave-per-row), final GEMM ----
  y_mfma_kernel<<<dim3(Tc / 128, Bc * 8), 256, 0, stream>>>(qb, attnT);
  ln_mod_silu_wave_kernel<<<Mq / 4, 256, 0, stream>>>(qb, ssb, onorm_g, onorm_b);
  gemm2_kernel<1, 32><<<(Dc / 128) * (Mq / 256), 512, 0, stream>>>(
      qb, Wo_t, bo, nullptr, 0, out, Mq, Dc, x);
}

// Round 18
// 456.041 us; speedup vs baseline: 1.0023x; 1.0023x over previous
//
#include <hip/hip_runtime.h>
#include <hip/hip_bf16.h>
#include <math.h>

namespace {

constexpr int Bc  = 32;
constexpr int Tc  = 1024;
constexpr int Dc  = 1024;
constexpr int Nt  = 77;
constexpr int Lc  = 768;
constexpr int HDc = 128;
constexpr int TEDc = 2048;
constexpr float EPSc = 1e-5f;

typedef __attribute__((ext_vector_type(8))) short bf16x8;
typedef __attribute__((ext_vector_type(8))) unsigned short u16x8;
typedef __attribute__((ext_vector_type(4))) float f32x4;

__device__ __forceinline__ float silu_f(float x) { return x / (1.f + __expf(-x)); }

__device__ __forceinline__ unsigned short f2bf(float f) {
  unsigned u = __float_as_uint(f);
  return (unsigned short)((u + 0x7fffu + ((u >> 16) & 1u)) >> 16);
}
__device__ __forceinline__ float bf2f(unsigned short h) {
  return __uint_as_float(((unsigned)h) << 16);
}

__device__ __forceinline__ void gload16(const void* g, void* l) {
  __builtin_amdgcn_global_load_lds((const __attribute__((address_space(1))) void*)g,
                                   (__attribute__((address_space(3))) void*)l, 16, 0, 0);
}

// swizzle term for a 16-row x 64B LDS chunk (r8-verified: conflicts 8.39M -> 0)
__device__ __forceinline__ int rowswz(int r) {
  return (((r >> 3) & 1) << 1) | ((r >> 1) & 1);
}

// ---------- LayerNorm -> bf16, wave-per-row (no barriers; COLS template => regs) --------
template<int COLS>
__global__ __launch_bounds__(256) void ln_bf16_wave_kernel(
    const float* __restrict__ src, unsigned short* __restrict__ dst,
    const float* __restrict__ g, const float* __restrict__ b, int rows)
{
  constexpr int NJ = COLS / 256;
  const int row = blockIdx.x * 4 + (threadIdx.x >> 6);
  if (row >= rows) return;
  const int lane = threadIdx.x & 63;
  const float* p = src + (size_t)row * COLS;
  float4 v[NJ];
  float s = 0.f, sq = 0.f;
  #pragma unroll
  for (int j = 0; j < NJ; j++) {
    v[j] = *reinterpret_cast<const float4*>(p + (j * 64 + lane) * 4);
    s  += v[j].x + v[j].y + v[j].z + v[j].w;
    sq += v[j].x * v[j].x + v[j].y * v[j].y + v[j].z * v[j].z + v[j].w * v[j].w;
  }
  #pragma unroll
  for (int o = 32; o > 0; o >>= 1) { s += __shfl_xor(s, o); sq += __shfl_xor(sq, o); }
  const float mean = s / COLS;
  const float rstd = rsqrtf(sq / COLS - mean * mean + EPSc);
  #pragma unroll
  for (int j = 0; j < NJ; j++) {
    const int c = (j * 64 + lane) * 4;
    ushort4 o4;
    o4.x = f2bf((v[j].x - mean) * rstd * g[c + 0] + b[c + 0]);
    o4.y = f2bf((v[j].y - mean) * rstd * g[c + 1] + b[c + 1]);
    o4.z = f2bf((v[j].z - mean) * rstd * g[c + 2] + b[c + 2]);
    o4.w = f2bf((v[j].w - mean) * rstd * g[c + 3] + b[c + 3]);
    *reinterpret_cast<ushort4*>(dst + (size_t)row * COLS + c) = o4;
  }
}

// ---------- transpose-convert, two matrices selected by blockIdx.z ----------------------
__global__ __launch_bounds__(256) void convT2_bf16_kernel(
    const float* __restrict__ W0, unsigned short* __restrict__ T0,
    const float* __restrict__ W1, unsigned short* __restrict__ T1, int K, int N)
{
  __shared__ float t[32][33];
  const float* W = blockIdx.z ? W1 : W0;
  unsigned short* Wt = blockIdx.z ? T1 : T0;
  const int n0 = blockIdx.x * 32, k0 = blockIdx.y * 32;
  const int tx = threadIdx.x & 31, ty = threadIdx.x >> 5;
  #pragma unroll
  for (int dy = 0; dy < 32; dy += 8)
    t[ty + dy][tx] = W[(size_t)(k0 + ty + dy) * N + n0 + tx];
  __syncthreads();
  #pragma unroll
  for (int dy = 0; dy < 32; dy += 8)
    Wt[(size_t)(n0 + ty + dy) * K + k0 + tx] = f2bf(t[tx][ty + dy]);
}

// ---------- bf16 MFMA GEMM, 256x128 tile, 8 waves, 3-deep pipeline, counted vmcnt -------
// (r12 core — best-measured passing GEMM across 13 structural variants this session)
template<int EPI, int NT>
__global__ __launch_bounds__(512, 4) void gemm2_kernel(
    const unsigned short* __restrict__ A, const unsigned short* __restrict__ Bt,
    const float* __restrict__ bias, const float* __restrict__ bias2, int bsplit,
    void* __restrict__ Cout, int M, int N, const float* __restrict__ xres)
{
  constexpr int K = NT * 32;
  __shared__ unsigned short lds[36864];   // 72 KB (EPI2 reuses [0,32768) for C-tile)
  const int tid = threadIdx.x, wid = tid >> 6, lane = tid & 63;
  const int ntx = N >> 7;
  int swz = blockIdx.x;
  const int nwg = gridDim.x;
  if ((nwg & 7) == 0) { const int cpx = nwg >> 3; swz = (swz & 7) * cpx + (swz >> 3); }
  const int bx = swz % ntx, by = swz / ntx;
  const int bm0 = by << 8, bn0 = bx << 7;
  const int wr = wid >> 1, wc = wid & 1, lhi = lane >> 4, llo = lane & 15;

  const int srow = lane >> 2;
  const int scol = (((lane & 3) ^ rowswz(srow)) * 8);
  int ar0 = bm0 + wid * 32 + srow;      if (ar0 >= M) ar0 = M - 1;
  int ar1 = bm0 + wid * 32 + 16 + srow; if (ar1 >= M) ar1 = M - 1;
  const int br = bn0 + wid * 16 + srow;
  const unsigned short* Ag0 = A  + (size_t)ar0 * K + scol;
  const unsigned short* Ag1 = A  + (size_t)ar1 * K + scol;
  const unsigned short* Bg  = Bt + (size_t)br  * K + scol;
  const int alc0 = (wid * 2) * 512, alc1 = (wid * 2 + 1) * 512, blc = wid * 512;
  const int rx = rowswz(llo);
  const int aoff = wr * 2048 + llo * 32 + ((lhi ^ rx) * 8);
  const int boff = wc * 2048 + llo * 32 + ((lhi ^ rx) * 8);

  f32x4 acc[4][4] = {};

  gload16(Ag0,      &lds[alc0]);
  gload16(Ag1,      &lds[alc1]);
  gload16(Bg,       &lds[24576 + blc]);
  gload16(Ag0 + 32, &lds[8192 + alc0]);
  gload16(Ag1 + 32, &lds[8192 + alc1]);
  gload16(Bg  + 32, &lds[24576 + 4096 + blc]);

  for (int t = 0; t < NT; t += 3) {
    #pragma unroll
    for (int j = 0; j < 3; j++) {
      const int tt = t + j;
      if (tt < NT) {
        if (tt + 2 < NT) {
          const int k2 = (tt + 2) << 5;
          constexpr int PB0 = 2, PB1 = 0, PB2 = 1;
          const int pb = (j == 0) ? PB0 : (j == 1) ? PB1 : PB2;
          gload16(Ag0 + k2, &lds[pb * 8192 + alc0]);
          gload16(Ag1 + k2, &lds[pb * 8192 + alc1]);
          gload16(Bg  + k2, &lds[24576 + pb * 4096 + blc]);
          asm volatile("s_waitcnt vmcnt(6)" ::: "memory");
        } else if (tt + 1 < NT) {
          asm volatile("s_waitcnt vmcnt(3)" ::: "memory");
        } else {
          asm volatile("s_waitcnt vmcnt(0)" ::: "memory");
        }
        __builtin_amdgcn_s_barrier();
        bf16x8 a_[4], b_[4];
        #pragma unroll
        for (int mi = 0; mi < 4; mi++)
          a_[mi] = *(const bf16x8*)(&lds[j * 8192 + aoff + mi * 512]);
        #pragma unroll
        for (int ni = 0; ni < 4; ni++)
          b_[ni] = *(const bf16x8*)(&lds[24576 + j * 4096 + boff + ni * 512]);
        __builtin_amdgcn_s_setprio(1);
        #pragma unroll
        for (int mi = 0; mi < 4; mi++)
          #pragma unroll
          for (int ni = 0; ni < 4; ni++)
            acc[mi][ni] = __builtin_amdgcn_mfma_f32_16x16x32_bf16(a_[mi], b_[ni], acc[mi][ni], 0, 0, 0);
        __builtin_amdgcn_s_setprio(0);
        __builtin_amdgcn_s_barrier();
      }
    }
  }

  if constexpr (EPI != 2) {
    #pragma unroll
    for (int mi = 0; mi < 4; mi++) {
      #pragma unroll
      for (int ni = 0; ni < 4; ni++) {
        const int col = bn0 + wc * 64 + ni * 16 + llo;
        const float bs = (bsplit > 0 && col >= bsplit) ? bias2[col - bsplit] : bias[col];
        #pragma unroll
        for (int r = 0; r < 4; r++) {
          const int row = bm0 + wr * 64 + mi * 16 + lhi * 4 + r;
          if (row < M) {
            float v = acc[mi][ni][r] + bs;
            if (EPI == 1) v += xres[(size_t)row * N + col];
            ((float*)Cout)[(size_t)row * N + col] = v;
          }
        }
      }
    }
  } else {
    // ---- fused head-dim softmax epilogue (tile N-width == head_dim == 128) ----
    __syncthreads();
    #pragma unroll
    for (int mi = 0; mi < 4; mi++) {
      #pragma unroll
      for (int ni = 0; ni < 4; ni++) {
        const int col = wc * 64 + ni * 16 + llo;
        const float bs = bias[bn0 + col];
        #pragma unroll
        for (int r = 0; r < 4; r++) {
          const int row = wr * 64 + mi * 16 + lhi * 4 + r;
          lds[row * 128 + (col ^ ((row & 7) << 3))] = f2bf(acc[mi][ni][r] + bs);
        }
      }
    }
    __syncthreads();
    const int row = tid >> 1, cb = (tid & 1) * 64;
    const int sw = (row & 7) << 3;
    float mx = -1e30f;
    #pragma unroll
    for (int g = 0; g < 8; g++) {
      u16x8 u = *(const u16x8*)(&lds[row * 128 + ((cb + g * 8) ^ sw)]);
      #pragma unroll
      for (int j = 0; j < 8; j++) mx = fmaxf(mx, bf2f(u[j]));
    }
    mx = fmaxf(mx, __shfl_xor(mx, 1));
    float ssum = 0.f;
    #pragma unroll
    for (int g = 0; g < 8; g++) {
      unsigned short* p = &lds[row * 128 + ((cb + g * 8) ^ sw)];
      u16x8 u = *(const u16x8*)p;
      u16x8 e;
      #pragma unroll
      for (int j = 0; j < 8; j++) {
        float ev = __expf(bf2f(u[j]) - mx);
        ssum += ev;
        e[j] = f2bf(ev);
      }
      *(u16x8*)p = e;
    }
    ssum += __shfl_xor(ssum, 1);
    const float inv = 1.f / ssum;
    unsigned short* Cb = (unsigned short*)Cout;
    #pragma unroll
    for (int g = 0; g < 8; g++) {
      u16x8 u = *(const u16x8*)(&lds[row * 128 + ((cb + g * 8) ^ sw)]);
      u16x8 o;
      #pragma unroll
      for (int j = 0; j < 8; j++) o[j] = f2bf(bf2f(u[j]) * inv);
      *(u16x8*)(&Cb[(size_t)(bm0 + row) * N + bn0 + cb + g * 8]) = o;
    }
  }
}

// ---------- attn: fused column-softmax(k over N) + attnT einsum (bf16 out) --------------
__global__ __launch_bounds__(256) void attn_fused_kernel(
    const float* __restrict__ kv, unsigned short* __restrict__ attnT) {
  const int bh = blockIdx.x;
  const int b = bh >> 3, h = bh & 7;
  __shared__ float ks[Nt][HDc];
  __shared__ float vs[Nt][HDc];
  const float* kb = kv + (size_t)b * Nt * 2048 + h * HDc;
  const float* vb = kv + (size_t)b * Nt * 2048 + 1024 + h * HDc;
  for (int i = threadIdx.x; i < Nt * HDc; i += 256) {
    const int n = i >> 7, d = i & 127;
    ks[n][d] = kb[(size_t)n * 2048 + d];
    vs[n][d] = vb[(size_t)n * 2048 + d];
  }
  __syncthreads();
  if (threadIdx.x < HDc) {
    const int d = threadIdx.x;
    float m = -1e30f;
    for (int n = 0; n < Nt; n++) m = fmaxf(m, ks[n][d]);
    float s = 0.f;
    for (int n = 0; n < Nt; n++) { float e = __expf(ks[n][d] - m); ks[n][d] = e; s += e; }
    const float inv = 1.f / s;
    for (int n = 0; n < Nt; n++) ks[n][d] *= inv;
  }
  __syncthreads();
  const int tx = threadIdx.x & 15, ty = threadIdx.x >> 4;
  float acc[8][8] = {};
  for (int n = 0; n < Nt; n++) {
    float a[8], w[8];
    #pragma unroll
    for (int i = 0; i < 8; i++) a[i] = vs[n][ty + 16 * i];
    #pragma unroll
    for (int j = 0; j < 8; j++) w[j] = ks[n][tx + 16 * j];
    #pragma unroll
    for (int i = 0; i < 8; i++)
      #pragma unroll
      for (int j = 0; j < 8; j++)
        acc[i][j] += a[i] * w[j];
  }
  unsigned short* ab = attnT + (size_t)bh * HDc * HDc;
  #pragma unroll
  for (int i = 0; i < 8; i++)
    #pragma unroll
    for (int j = 0; j < 8; j++)
      ab[(size_t)(ty + 16 * i) * HDc + tx + 16 * j] = f2bf(acc[i][j]);
}

// ---------- y = q @ attn per (b,h), MFMA 2-phase, coalesced epilogue, in place ----------
__global__ __launch_bounds__(256) void y_mfma_kernel(
    unsigned short* __restrict__ q, const unsigned short* __restrict__ attnT)
{
  __shared__ unsigned short lds[16384];
  const int tid = threadIdx.x, wid = tid >> 6, lane = tid & 63;
  const int bh = blockIdx.y, b = bh >> 3, h = bh & 7;
  const int bm0 = blockIdx.x << 7;
  const int wr = wid >> 1, wc = wid & 1, lhi = lane >> 4, llo = lane & 15;

  unsigned short* Abase = q + ((size_t)b * Tc) * Dc + h * HDc;
  const unsigned short* Btb = attnT + (size_t)bh * HDc * HDc;

  const int srow = lane >> 2, scol = (lane & 3) * 8;
  const int ar0 = bm0 + wid * 32 + srow, ar1 = ar0 + 16;
  const int br0 = wid * 32 + srow,       br1 = br0 + 16;
  const unsigned short* Ag0 = Abase + (size_t)ar0 * Dc + scol;
  const unsigned short* Ag1 = Abase + (size_t)ar1 * Dc + scol;
  const unsigned short* Bg0 = Btb + (size_t)br0 * HDc + scol;
  const unsigned short* Bg1 = Btb + (size_t)br1 * HDc + scol;
  const int lc0 = (wid * 2 + 0) * 512, lc1 = (wid * 2 + 1) * 512;
  const int aoff = wr * 2048 + llo * 32 + lhi * 8;
  const int boff = wc * 2048 + llo * 32 + lhi * 8;

  f32x4 acc[4][4] = {};

  gload16(Ag0, &lds[lc0]);
  gload16(Ag1, &lds[lc1]);
  gload16(Bg0, &lds[8192 + lc0]);
  gload16(Bg1, &lds[8192 + lc1]);
  __syncthreads();

  int cur = 0;
  for (int t = 1; t < 4; ++t) {
    const int nb = cur ^ 1;
    const int k0 = t << 5;
    gload16(Ag0 + k0, &lds[nb * 4096 + lc0]);
    gload16(Ag1 + k0, &lds[nb * 4096 + lc1]);
    gload16(Bg0 + k0, &lds[8192 + nb * 4096 + lc0]);
    gload16(Bg1 + k0, &lds[8192 + nb * 4096 + lc1]);
    bf16x8 a_[4], b_[4];
    #pragma unroll
    for (int mi = 0; mi < 4; mi++) a_[mi] = *(const bf16x8*)(&lds[cur * 4096 + aoff + mi * 512]);
    #pragma unroll
    for (int ni = 0; ni < 4; ni++) b_[ni] = *(const bf16x8*)(&lds[8192 + cur * 4096 + boff + ni * 512]);
    #pragma unroll
    for (int mi = 0; mi < 4; mi++)
      #pragma unroll
      for (int ni = 0; ni < 4; ni++)
        acc[mi][ni] = __builtin_amdgcn_mfma_f32_16x16x32_bf16(a_[mi], b_[ni], acc[mi][ni], 0, 0, 0);
    __syncthreads();
    cur = nb;
  }
  {
    bf16x8 a_[4], b_[4];
    #pragma unroll
    for (int mi = 0; mi < 4; mi++) a_[mi] = *(const bf16x8*)(&lds[cur * 4096 + aoff + mi * 512]);
    #pragma unroll
    for (int ni = 0; ni < 4; ni++) b_[ni] = *(const bf16x8*)(&lds[8192 + cur * 4096 + boff + ni * 512]);
    #pragma unroll
    for (int mi = 0; mi < 4; mi++)
      #pragma unroll
      for (int ni = 0; ni < 4; ni++)
        acc[mi][ni] = __builtin_amdgcn_mfma_f32_16x16x32_bf16(a_[mi], b_[ni], acc[mi][ni], 0, 0, 0);
  }

  __syncthreads();
  #pragma unroll
  for (int mi = 0; mi < 4; mi++) {
    #pragma unroll
    for (int ni = 0; ni < 4; ni++) {
      const int col = wc * 64 + ni * 16 + llo;
      #pragma unroll
      for (int r = 0; r < 4; r++) {
        const int row = wr * 64 + mi * 16 + lhi * 4 + r;
        lds[row * 128 + (col ^ ((row & 7) << 3))] = f2bf(acc[mi][ni][r]);
      }
    }
  }
  __syncthreads();
  const int row = tid >> 1, cb = (tid & 1) * 64;
  const int sw = (row & 7) << 3;
  #pragma unroll
  for (int g = 0; g < 8; g++) {
    u16x8 u = *(const u16x8*)(&lds[row * 128 + ((cb + g * 8) ^ sw)]);
    *(u16x8*)(&Abase[(size_t)(bm0 + row) * Dc + cb + g * 8]) = u;
  }
}

// ---------- LN(y)*(1+scale)+shift -> SiLU, wave-per-row, in place (bf16) ----------------
__global__ __launch_bounds__(256) void ln_mod_silu_wave_kernel(
    unsigned short* __restrict__ y, const float* __restrict__ ss,
    const float* __restrict__ g, const float* __restrict__ bvec) {
  const int row = blockIdx.x * 4 + (threadIdx.x >> 6);
  const int lane = threadIdx.x & 63;
  const int b = row >> 10;
  unsigned short* p = y + (size_t)row * Dc;
  float4 v[4];
  float s = 0.f, sq = 0.f;
  #pragma unroll
  for (int j = 0; j < 4; j++) {
    ushort4 u = *reinterpret_cast<const ushort4*>(p + (j * 64 + lane) * 4);
    v[j] = make_float4(bf2f(u.x), bf2f(u.y), bf2f(u.z), bf2f(u.w));
    s  += v[j].x + v[j].y + v[j].z + v[j].w;
    sq += v[j].x * v[j].x + v[j].y * v[j].y + v[j].z * v[j].z + v[j].w * v[j].w;
  }
  #pragma unroll
  for (int o = 32; o > 0; o >>= 1) { s += __shfl_xor(s, o); sq += __shfl_xor(sq, o); }
  const float mean = s / 1024.f;
  const float rstd = rsqrtf(sq / 1024.f - mean * mean + EPSc);
  const float* ssb = ss + (size_t)b * 2048;
  #pragma unroll
  for (int j = 0; j < 4; j++) {
    const int c = (j * 64 + lane) * 4;
    ushort4 o4;
    float t0 = (v[j].x - mean) * rstd * g[c + 0] + bvec[c + 0];
    float t1 = (v[j].y - mean) * rstd * g[c + 1] + bvec[c + 1];
    float t2 = (v[j].z - mean) * rstd * g[c + 2] + bvec[c + 2];
    float t3 = (v[j].w - mean) * rstd * g[c + 3] + bvec[c + 3];
    o4.x = f2bf(silu_f(t0 * (1.f + ssb[c + 0]) + ssb[1024 + c + 0]));
    o4.y = f2bf(silu_f(t1 * (1.f + ssb[c + 1]) + ssb[1024 + c + 1]));
    o4.z = f2bf(silu_f(t2 * (1.f + ssb[c + 2]) + ssb[1024 + c + 2]));
    o4.w = f2bf(silu_f(t3 * (1.f + ssb[c + 3]) + ssb[1024 + c + 3]));
    *reinterpret_cast<ushort4*>(p + c) = o4;
  }
}

// ---------- emb projection: silu precompute, split-K partial GEMM, reduce ---------------
__global__ __launch_bounds__(256) void silu_emb_kernel(
    const float* __restrict__ emb, float* __restrict__ sile) {
  const int i = (blockIdx.x * 256 + threadIdx.x) * 4;
  float4 v = *reinterpret_cast<const float4*>(emb + i);
  v.x = silu_f(v.x); v.y = silu_f(v.y); v.z = silu_f(v.z); v.w = silu_f(v.w);
  *reinterpret_cast<float4*>(sile + i) = v;
}

__global__ __launch_bounds__(256) void emb_part_kernel(
    const float* __restrict__ sile, const float* __restrict__ W,
    float* __restrict__ part) {
  const int split = blockIdx.y;
  const int n = blockIdx.x * 256 + threadIdx.x;
  const int k0 = split * 64;
  const float* se = sile + k0;
  const float* Wp = W + (size_t)k0 * (2 * Dc) + n;
  float acc[32] = {};
  for (int kk = 0; kk < 64; kk++) {
    const float w = Wp[(size_t)kk * (2 * Dc)];
    #pragma unroll
    for (int m = 0; m < 32; m++)
      acc[m] = fmaf(se[m * TEDc + kk], w, acc[m]);
  }
  float* pp = part + (size_t)split * 32 * (2 * Dc) + n;
  #pragma unroll
  for (int m = 0; m < 32; m++) pp[(size_t)m * (2 * Dc)] = acc[m];
}

__global__ __launch_bounds__(256) void emb_reduce_kernel(
    const float* __restrict__ part, const float* __restrict__ bias,
    float* __restrict__ ssb) {
  const int i = blockIdx.x * 256 + threadIdx.x;
  const int n = i & (2 * Dc - 1);
  float s = bias[n];
  #pragma unroll 8
  for (int sp = 0; sp < 32; sp++) s += part[(size_t)sp * 32 * (2 * Dc) + i];
  ssb[i] = s;
}

}  // namespace

extern "C" void kernel_launch(void* const* d_in, const int* in_sizes, int n_in,
                              void* d_out, int out_size, void* d_ws, size_t ws_size,
                              hipStream_t stream) {
  const float* x       = (const float*)d_in[0];
  const float* xf      = (const float*)d_in[1];
  const float* emb     = (const float*)d_in[2];
  const float* norm_g  = (const float*)d_in[3];
  const float* norm_b  = (const float*)d_in[4];
  const float* tnorm_g = (const float*)d_in[5];
  const float* tnorm_b = (const float*)d_in[6];
  const float* Wq      = (const float*)d_in[7];
  const float* bq      = (const float*)d_in[8];
  const float* Wk      = (const float*)d_in[9];
  const float* bk      = (const float*)d_in[10];
  const float* Wv      = (const float*)d_in[11];
  const float* bv_     = (const float*)d_in[12];
  const float* emb_W   = (const float*)d_in[13];
  const float* emb_b   = (const float*)d_in[14];
  const float* onorm_g = (const float*)d_in[15];
  const float* onorm_b = (const float*)d_in[16];
  const float* Wo      = (const float*)d_in[17];
  const float* bo      = (const float*)d_in[18];
  float* out = (float*)d_out;

  char* ws = (char*)d_ws;
  unsigned short* Ab = (unsigned short*)ws;                       // [32768][1024] bf16
  char* R = ws;                                                   // aliased after q-GEMM
  unsigned short* qb   = (unsigned short*)(ws + 67108864);        // [32768][1024] bf16
  unsigned short* Wq_t = (unsigned short*)(ws + 134217728);
  unsigned short* Wk_t = (unsigned short*)(ws + 136314880);       // [Wk_t|Wv_t] contiguous
  unsigned short* Wv_t = (unsigned short*)(ws + 137887744);
  unsigned short* Wo_t = (unsigned short*)(ws + 139460608);
  float*          ssb  = (float*)(ws + 141557760);                // [32][2048]
  float*          sile = (float*)(ws + 141819904);                // [32][2048]
  float*          part = (float*)(ws + 142082048);                // [32][32][2048]
  // kv-phase aliases inside R (stream-serial after q-GEMM consumed Ab):
  unsigned short* xfb   = (unsigned short*)(R);                   // [2464][768] bf16
  float*          kv    = (float*)(R + 3784704);                  // [2464][2048] f32
  unsigned short* attnT = (unsigned short*)(R + 23969792);        // [256][128][128] bf16

  const int Mq  = Bc * Tc;   // 32768
  const int Mkv = Bc * Nt;   // 2464

  // ---- q path ----
  ln_bf16_wave_kernel<1024><<<Mq / 4, 256, 0, stream>>>(x, Ab, norm_g, norm_b, Mq);
  convT2_bf16_kernel<<<dim3(Dc / 32, Dc / 32, 2), 256, 0, stream>>>(Wq, Wq_t, Wo, Wo_t, Dc, Dc);
  convT2_bf16_kernel<<<dim3(Dc / 32, Lc / 32, 2), 256, 0, stream>>>(Wk, Wk_t, Wv, Wv_t, Lc, Dc);

  // q = softmax_head(LN(x) @ Wq + bq), fused epilogue   (K=1024 -> NT=32)
  gemm2_kernel<2, 32><<<(Dc / 128) * (Mq / 256), 512, 0, stream>>>(
      Ab, Wq_t, bq, nullptr, 0, qb, Mq, Dc, nullptr);

  // ---- kv path (merged k+v GEMM; Wk_t|Wv_t contiguous as [2048][768]; K=768 -> NT=24) --
  ln_bf16_wave_kernel<768><<<Mkv / 4, 256, 0, stream>>>(xf, xfb, tnorm_g, tnorm_b, Mkv);
  gemm2_kernel<0, 24><<<(2048 / 128) * ((Mkv + 255) / 256), 512, 0, stream>>>(
      xfb, Wk_t, bk, bv_, 1024, kv, Mkv, 2048, nullptr);
  attn_fused_kernel<<<Bc * 8, 256, 0, stream>>>(kv, attnT);

  // ---- FiLM params: split-K ----
  silu_emb_kernel<<<(Bc * TEDc) / 1024, 256, 0, stream>>>(emb, sile);
  emb_part_kernel<<<dim3(8, 32), 256, 0, stream>>>(sile, emb_W, part);
  emb_reduce_kernel<<<(Bc * 2 * Dc) / 256, 256, 0, stream>>>(part, emb_b, ssb);

  // ---- y = q @ attn (MFMA, in place), LN+mod+SiLU (wave-per-row), final GEMM ----
  y_mfma_kernel<<<dim3(Tc / 128, Bc * 8), 256, 0, stream>>>(qb, attnT);
  ln_mod_silu_wave_kernel<<<Mq / 4, 256, 0, stream>>>(qb, ssb, onorm_g, onorm_b);
  gemm2_kernel<1, 32><<<(Dc / 128) * (Mq / 256), 512, 0, stream>>>(
      qb, Wo_t, bo, nullptr, 0, out, Mq, Dc, x);
}